// Round 1
// baseline (36.134 us; speedup 1.0000x reference)
//
#include <hip/hip_runtime.h>

// PureAddShiftMP: NK=3 one-hot 3x3 convs + center-crop == shifted channel-gather adds.
// offsets (dy,dx): p0=(-1,-1), p1=(-1,0), p2=(0,-1)
// out_g[n,o,y,x] = sum_k x[n,3o+k, y+dy_{(k+g)%3}, x+dx_{(k+g)%3}]

#define CIN 768
#define COUT 256
#define HWDIM 64
#define PLANE 4096            // 64*64
#define PER_GROUP 8388608L    // 8*256*64*64

__global__ __launch_bounds__(256) void shift3_kernel(
    const float* __restrict__ xin, float* __restrict__ out)
{
    // thread t handles 4 consecutive x pixels of one (n, o, y)
    unsigned t = blockIdx.x * 256u + threadIdx.x;   // 0 .. 2097151
    int xq = (int)(t & 15);          // x / 4
    int yy = (int)((t >> 4) & 63);
    int o  = (int)((t >> 10) & 255);
    int n  = (int)(t >> 18);
    int x0 = xq << 2;

    const float* base = xin + (((size_t)n * CIN + 3 * (size_t)o) << 12);
    const bool ytop  = (yy == 0);
    const bool xleft = (x0 == 0);

    float4 p0[3], p1[3], p2[3];
    #pragma unroll
    for (int k = 0; k < 3; ++k) {
        const float* c = base + ((size_t)k << 12);
        const int rm = (yy - 1) << 6;   // row y-1
        const int r  = yy << 6;         // row y
        float4 M, R;
        float m0, r0;
        if (!ytop) {
            M  = *reinterpret_cast<const float4*>(c + rm + x0);
            m0 = xleft ? 0.0f : c[rm + x0 - 1];
        } else {
            M  = make_float4(0.f, 0.f, 0.f, 0.f);
            m0 = 0.0f;
        }
        R  = *reinterpret_cast<const float4*>(c + r + x0);
        r0 = xleft ? 0.0f : c[r + x0 - 1];

        p1[k] = M;                                   // (-1, 0)
        p0[k] = make_float4(m0, M.x, M.y, M.z);      // (-1,-1)
        p2[k] = make_float4(r0, R.x, R.y, R.z);      // ( 0,-1)
    }

    float4 o0, o1, o2;
    o0.x = p0[0].x + p1[1].x + p2[2].x;
    o0.y = p0[0].y + p1[1].y + p2[2].y;
    o0.z = p0[0].z + p1[1].z + p2[2].z;
    o0.w = p0[0].w + p1[1].w + p2[2].w;

    o1.x = p1[0].x + p2[1].x + p0[2].x;
    o1.y = p1[0].y + p2[1].y + p0[2].y;
    o1.z = p1[0].z + p2[1].z + p0[2].z;
    o1.w = p1[0].w + p2[1].w + p0[2].w;

    o2.x = p2[0].x + p0[1].x + p1[2].x;
    o2.y = p2[0].y + p0[1].y + p1[2].y;
    o2.z = p2[0].z + p0[1].z + p1[2].z;
    o2.w = p2[0].w + p0[1].w + p1[2].w;

    size_t oidx = (((size_t)n * COUT + (size_t)o) << 12) + ((size_t)yy << 6) + (size_t)x0;
    *reinterpret_cast<float4*>(out + oidx)                 = o0;
    *reinterpret_cast<float4*>(out + oidx + PER_GROUP)     = o1;
    *reinterpret_cast<float4*>(out + oidx + 2 * PER_GROUP) = o2;
}

extern "C" void kernel_launch(void* const* d_in, const int* in_sizes, int n_in,
                              void* d_out, int out_size, void* d_ws, size_t ws_size,
                              hipStream_t stream) {
    const float* x = (const float*)d_in[0];
    float* out = (float*)d_out;
    // total threads = 8*256*64*16 = 2,097,152 -> 8192 blocks of 256
    shift3_kernel<<<8192, 256, 0, stream>>>(x, out);
}

// Round 2
// 34.342 us; speedup vs baseline: 1.0522x; 1.0522x over previous
//
#include <hip/hip_runtime.h>

// PureAddShiftMP: NK=3 one-hot 3x3 convs + center-crop == shifted channel-gather adds.
// offsets (dy,dx): p0=(-1,-1), p1=(-1,0), p2=(0,-1)
// out_g[n,o,y,x] = sum_k x[n,3o+k, y+dy_{(k+g)%3}, x+dx_{(k+g)%3}]

#define CIN 768
#define COUT 256
#define PER_GROUP 8388608L    // 8*256*64*64

typedef float f4 __attribute__((ext_vector_type(4)));

__global__ __launch_bounds__(256) void shift3_kernel(
    const float* __restrict__ xin, float* __restrict__ out)
{
    // thread t handles 4 consecutive x pixels of one (n, o, y)
    unsigned t = blockIdx.x * 256u + threadIdx.x;   // 0 .. 2097151
    int xq = (int)(t & 15);          // x / 4
    int yy = (int)((t >> 4) & 63);
    int o  = (int)((t >> 10) & 255);
    int n  = (int)(t >> 18);
    int x0 = xq << 2;

    const float* base = xin + (((size_t)n * CIN + 3 * (size_t)o) << 12);
    const float ymask = (yy == 0) ? 0.0f : 1.0f;   // row y-1 exists?
    const float xmask = (xq == 0) ? 0.0f : 1.0f;   // col x-1 exists?
    const int rm = ((yy == 0) ? 0 : (yy - 1)) << 6; // clamped row y-1 (masked later)
    const int r  = yy << 6;                          // row y

    f4 p0[3], p1[3], p2[3];
    #pragma unroll
    for (int k = 0; k < 3; ++k) {
        const float* c = base + (k << 12);
        f4 M = *reinterpret_cast<const f4*>(c + rm + x0);
        f4 R = *reinterpret_cast<const f4*>(c + r + x0);
        M.x *= ymask; M.y *= ymask; M.z *= ymask; M.w *= ymask;
        // neighbor-lane shift: previous lane (same row) holds x0-1 in its .w
        float m0 = __shfl_up(M.w, 1, 64) * xmask;
        float r0 = __shfl_up(R.w, 1, 64) * xmask;
        p1[k] = M;                      // (-1, 0)
        p0[k] = (f4){m0, M.x, M.y, M.z}; // (-1,-1)
        p2[k] = (f4){r0, R.x, R.y, R.z}; // ( 0,-1)
    }

    f4 o0 = p0[0] + p1[1] + p2[2];
    f4 o1 = p1[0] + p2[1] + p0[2];
    f4 o2 = p2[0] + p0[1] + p1[2];

    size_t oidx = (((size_t)n * COUT + (size_t)o) << 12) + ((size_t)yy << 6) + (size_t)x0;
    // outputs are never re-read: non-temporal stores keep x resident in L3
    __builtin_nontemporal_store(o0, reinterpret_cast<f4*>(out + oidx));
    __builtin_nontemporal_store(o1, reinterpret_cast<f4*>(out + oidx + PER_GROUP));
    __builtin_nontemporal_store(o2, reinterpret_cast<f4*>(out + oidx + 2 * PER_GROUP));
}

extern "C" void kernel_launch(void* const* d_in, const int* in_sizes, int n_in,
                              void* d_out, int out_size, void* d_ws, size_t ws_size,
                              hipStream_t stream) {
    const float* x = (const float*)d_in[0];
    float* out = (float*)d_out;
    // total threads = 8*256*64*16 = 2,097,152 -> 8192 blocks of 256
    shift3_kernel<<<8192, 256, 0, stream>>>(x, out);
}